// Round 4
// baseline (1234.035 us; speedup 1.0000x reference)
//
#include <hip/hip_runtime.h>
#include <hip/hip_cooperative_groups.h>
#include <stdint.h>

namespace cg = cooperative_groups;

// ---------------------------------------------------------------------------
// BatchWhiten: out = x @ inv_sqrtm(max(0.1*running + 0.9*(x^T x)/N, 1e-5))
// x: [262144, 512] fp32, running: [512,512] fp32, out: [262144,512] fp32
// ---------------------------------------------------------------------------

#define N_ROWS 262144
#define D 512
#define NS_ITERS 5
#define CK_CHUNKS 64
#define CK_ROWS (N_ROWS / CK_CHUNKS)  // 4096
#define CK_STEPS (CK_ROWS / 32)       // 128

typedef float f32x4 __attribute__((ext_vector_type(4)));
typedef short s16x8 __attribute__((ext_vector_type(8)));
typedef short s16x4 __attribute__((ext_vector_type(4)));
typedef __bf16 bf16x8 __attribute__((ext_vector_type(8)));

static __device__ __forceinline__ unsigned short f2bf(float f) {
  unsigned u = __float_as_uint(f);
  u += 0x7FFFu + ((u >> 16) & 1u);  // RNE
  return (unsigned short)(u >> 16);
}

static __device__ __forceinline__ f32x4 mfma16(s16x8 a, s16x8 b, f32x4 c) {
  return __builtin_amdgcn_mfma_f32_16x16x32_bf16(
      __builtin_bit_cast(bf16x8, a), __builtin_bit_cast(bf16x8, b), c, 0, 0, 0);
}

#define SWZ4(c) (((c) ^ ((c) >> 2)) & 3)
#define SWZ8(c) (((c) ^ ((c) >> 3)) & 7)

// ---------------------------------------------------------------------------
// Kernel 1: C += x^T x, split-K, bf16 MFMA, upper tiles (mb<=nb) only.
// grid 640, XCD-swizzled. Diagonal works (mb==nb) additionally dump their
// staged bf16 tile to xb16 (row-major [N][512] bf16) — full coverage, once.
// ---------------------------------------------------------------------------
__global__ __launch_bounds__(256) void covar_k(const float* __restrict__ x,
                                               float* __restrict__ C,
                                               short* __restrict__ xb16) {
  __shared__ short ldsA[128 * 32];
  __shared__ short ldsB[128 * 32];

  const int hw = blockIdx.x;
  const int work = (hw & 7) * 80 + (hw >> 3);
  int t = work % 10, mb = 0, rl = 4;
  while (t >= rl) { t -= rl; ++mb; --rl; }
  const int nb = mb + t;
  const int chunk = work / 10;

  const int tid = threadIdx.x;
  const int c2 = (tid & 63) * 2;  // 0,2,..,126
  const int kh = tid >> 6;        // 0..3 (k-chunk of 8)

  const int lane = tid & 63;
  const int wave = tid >> 6;
  const int wr = wave >> 1, wc = wave & 1;
  const int l15 = lane & 15, g = lane >> 4;

  const bool dump = (xb16 != nullptr) && (nb == mb);

  f32x4 acc[4][4];
#pragma unroll
  for (int i = 0; i < 4; ++i)
#pragma unroll
    for (int j = 0; j < 4; ++j) acc[i][j] = f32x4{0.f, 0.f, 0.f, 0.f};

  const size_t kbase0 = (size_t)chunk * CK_ROWS;

  for (int st = 0; st < CK_STEPS; ++st) {
    const size_t k0 = kbase0 + (size_t)st * 32;
    __syncthreads();
    {  // stage M-block
      const float* src = x + (k0 + kh * 8) * D + mb * 128 + c2;
      s16x8 p0, p1;
#pragma unroll
      for (int q = 0; q < 8; ++q) {
        float2 v = *(const float2*)(src + (size_t)q * D);
        p0[q] = (short)f2bf(v.x);
        p1[q] = (short)f2bf(v.y);
      }
      *(s16x8*)(ldsA + c2 * 32 + ((kh ^ SWZ4(c2)) << 3)) = p0;
      *(s16x8*)(ldsA + (c2 + 1) * 32 + ((kh ^ SWZ4(c2 + 1)) << 3)) = p1;
      if (dump) {
        uint32_t* xw = (uint32_t*)xb16;
        const size_t base = (k0 + kh * 8) * 256 + mb * 64 + (c2 >> 1);
#pragma unroll
        for (int q = 0; q < 8; ++q) {
          const uint32_t u =
              (uint32_t)(uint16_t)p0[q] | ((uint32_t)(uint16_t)p1[q] << 16);
          xw[base + (size_t)q * 256] = u;
        }
      }
    }
    if (nb != mb) {  // stage N-block
      const float* src = x + (k0 + kh * 8) * D + nb * 128 + c2;
      s16x8 p0, p1;
#pragma unroll
      for (int q = 0; q < 8; ++q) {
        float2 v = *(const float2*)(src + (size_t)q * D);
        p0[q] = (short)f2bf(v.x);
        p1[q] = (short)f2bf(v.y);
      }
      *(s16x8*)(ldsB + c2 * 32 + ((kh ^ SWZ4(c2)) << 3)) = p0;
      *(s16x8*)(ldsB + (c2 + 1) * 32 + ((kh ^ SWZ4(c2 + 1)) << 3)) = p1;
    }
    __syncthreads();

    const short* Bp = (nb != mb) ? ldsB : ldsA;
    s16x8 af[4], bfv[4];
#pragma unroll
    for (int mi = 0; mi < 4; ++mi) {
      int m = 64 * wr + 16 * mi + l15;
      af[mi] = *(const s16x8*)(ldsA + m * 32 + ((g ^ SWZ4(m)) << 3));
    }
#pragma unroll
    for (int nj = 0; nj < 4; ++nj) {
      int n = 64 * wc + 16 * nj + l15;
      bfv[nj] = *(const s16x8*)(Bp + n * 32 + ((g ^ SWZ4(n)) << 3));
    }
#pragma unroll
    for (int mi = 0; mi < 4; ++mi)
#pragma unroll
      for (int nj = 0; nj < 4; ++nj)
        acc[mi][nj] = mfma16(af[mi], bfv[nj], acc[mi][nj]);
  }

  // epilogue: atomic accumulate into upper tile (mb,nb)
#pragma unroll
  for (int mi = 0; mi < 4; ++mi)
#pragma unroll
    for (int nj = 0; nj < 4; ++nj) {
      const int n = nb * 128 + 64 * wc + 16 * nj + l15;
#pragma unroll
      for (int r = 0; r < 4; ++r) {
        const int m = mb * 128 + 64 * wr + 16 * mi + 4 * g + r;
        atomicAdd(&C[(size_t)m * D + n], acc[mi][nj][r]);
      }
    }
}

// ---------------------------------------------------------------------------
// 512x512x512 fp32 matmul body (32x32 tile / block, 2x2 per thread)
// ---------------------------------------------------------------------------
__device__ __forceinline__ void mm512_body(const float* A, const float* B,
                                           float* a00, float* a01, float* a10,
                                           float* a11, int rbase, int cbase) {
  __shared__ float As[32][36];
  __shared__ float Bs[32][36];
  const int t = threadIdx.x;
  const int tx = t & 15, ty = t >> 4;
  const int sr = t >> 3, sc = (t & 7) * 4;
  float c00 = 0.f, c01 = 0.f, c10 = 0.f, c11 = 0.f;
  for (int k0 = 0; k0 < D; k0 += 32) {
    __syncthreads();
    *(float4*)&As[sr][sc] = *(const float4*)(A + (size_t)(rbase + sr) * D + k0 + sc);
    *(float4*)&Bs[sr][sc] = *(const float4*)(B + (size_t)(k0 + sr) * D + cbase + sc);
    __syncthreads();
#pragma unroll
    for (int kk = 0; kk < 32; ++kk) {
      const float av0 = As[2 * ty][kk], av1 = As[2 * ty + 1][kk];
      const float2 bv = *(const float2*)&Bs[kk][2 * tx];
      c00 = fmaf(av0, bv.x, c00);
      c01 = fmaf(av0, bv.y, c01);
      c10 = fmaf(av1, bv.x, c10);
      c11 = fmaf(av1, bv.y, c11);
    }
  }
  *a00 = c00; *a01 = c01; *a10 = c10; *a11 = c11;
}

// ---------------------------------------------------------------------------
// Kernel 2 (cooperative, 256 blocks x 256 thr): prep (M, sMax) -> init (Y,Z)
// -> 5x coupled Newton-Schulz -> panel build. Replaces 13 launches.
// ---------------------------------------------------------------------------
__global__ __launch_bounds__(256) void fused_mat_k(
    const float* C, const float* run, float* M, unsigned* sMax, float* Ya,
    float* Yb, float* Za, float* Zb, float* T, short* panels) {
  cg::grid_group grid = cg::this_grid();
  const int b = blockIdx.x, t = threadIdx.x;

  // ---- prep: block b handles rows 2b, 2b+1 ----
  {
    const int r = 2 * b + (t >> 7);
    const int c0 = (t & 127) * 4;
    const float cs = 0.9f / (float)N_ROWS;
    const float4 rv = *(const float4*)&run[(size_t)r * D + c0];
    float v[4];
    float sum = 0.f;
#pragma unroll
    for (int e = 0; e < 4; ++e) {
      const int c = c0 + e;
      const int rr = r < c ? r : c, cc = r < c ? c : r;
      const float cv = C[(size_t)rr * D + cc];
      const float runv = (&rv.x)[e];
      const float val = fmaxf(0.1f * runv + cs * cv, 1e-5f);
      v[e] = val;
      sum += val;
    }
    *(float4*)&M[(size_t)r * D + c0] = make_float4(v[0], v[1], v[2], v[3]);
    __shared__ float red[256];
    red[t] = sum;
    __syncthreads();
    for (int off = 64; off > 0; off >>= 1) {
      if ((t & 127) < off) red[t] += red[t + off];
      __syncthreads();
    }
    if ((t & 127) == 0) atomicMax(sMax, __float_as_uint(red[t]));
  }
  grid.sync();
  const float s = __uint_as_float(*sMax);

  // ---- init: Y = M/s, Z = I ----
  {
    const float inv = 1.0f / s;
    const int i0 = (b * 256 + t) * 4;
    const float4 m4 = *(const float4*)&M[i0];
    *(float4*)&Ya[i0] =
        make_float4(m4.x * inv, m4.y * inv, m4.z * inv, m4.w * inv);
    const int row = i0 >> 9, col0 = i0 & 511;
    float4 z4 = make_float4(0.f, 0.f, 0.f, 0.f);
    if (row >= col0 && row < col0 + 4) (&z4.x)[row - col0] = 1.0f;
    *(float4*)&Za[i0] = z4;
  }
  grid.sync();

  // ---- coupled Newton-Schulz ----
  float *Y = Ya, *Z = Za, *Yn = Yb, *Zn = Zb;
  const int rbase = (b >> 4) * 32, cbase = (b & 15) * 32;
  const int tx = t & 15, ty = t >> 4;
  for (int it = 0; it < NS_ITERS; ++it) {
    float a00, a01, a10, a11;
    // T = 1.5 I - 0.5 (Z Y)
    mm512_body(Z, Y, &a00, &a01, &a10, &a11, rbase, cbase);
    {
      const int r0 = rbase + 2 * ty, c0 = cbase + 2 * tx;
      T[(size_t)r0 * D + c0] = (r0 == c0 ? 1.5f : 0.f) - 0.5f * a00;
      T[(size_t)r0 * D + c0 + 1] = (r0 == c0 + 1 ? 1.5f : 0.f) - 0.5f * a01;
      T[(size_t)(r0 + 1) * D + c0] = (r0 + 1 == c0 ? 1.5f : 0.f) - 0.5f * a10;
      T[(size_t)(r0 + 1) * D + c0 + 1] =
          (r0 + 1 == c0 + 1 ? 1.5f : 0.f) - 0.5f * a11;
    }
    grid.sync();
    // Yn = Y T
    mm512_body(Y, T, &a00, &a01, &a10, &a11, rbase, cbase);
    {
      const int r0 = rbase + 2 * ty, c0 = cbase + 2 * tx;
      Yn[(size_t)r0 * D + c0] = a00;
      Yn[(size_t)r0 * D + c0 + 1] = a01;
      Yn[(size_t)(r0 + 1) * D + c0] = a10;
      Yn[(size_t)(r0 + 1) * D + c0 + 1] = a11;
    }
    // Zn = T Z
    mm512_body(T, Z, &a00, &a01, &a10, &a11, rbase, cbase);
    {
      const int r0 = rbase + 2 * ty, c0 = cbase + 2 * tx;
      Zn[(size_t)r0 * D + c0] = a00;
      Zn[(size_t)r0 * D + c0 + 1] = a01;
      Zn[(size_t)(r0 + 1) * D + c0] = a10;
      Zn[(size_t)(r0 + 1) * D + c0 + 1] = a11;
    }
    grid.sync();
    float* tmp = Y; Y = Yn; Yn = tmp;
    tmp = Z; Z = Zn; Zn = tmp;
  }

  // ---- panel: B = Z / sqrt(s), pre-swizzled bf16 ----
  {
    const float rs = rsqrtf(s);
    const int i0 = (b * 256 + t) * 4;
    const float4 z4 = *(const float4*)&Z[i0];
#pragma unroll
    for (int e = 0; e < 4; ++e) {
      const int i = i0 + e;
      const int k = i >> 9, n = i & 511;
      const float v = (&z4.x)[e] * rs;
      const int nb_ = n >> 7, nl = n & 127;
      const int ks = k >> 6, kl = k & 63;
      const int ch = (kl >> 3) ^ SWZ8(nl), el = kl & 7;
      const size_t pi = (size_t)((nb_ * 8 + ks) * 128 + nl) * 64 + ch * 8 + el;
      panels[pi] = (short)f2bf(v);
    }
  }
}

// ---------------------------------------------------------------------------
// Kernel 3: out = x @ B. grid 8192 (XCD swizzle: 4 ct-sharers of a row panel
// co-dispatched on one XCD). USEBF: A from bf16 xb16 (no f2bf). Epilogue:
// per-wave LDS transpose -> lane-contiguous float4 nontemporal stores.
// ---------------------------------------------------------------------------
template <int USEBF>
__global__ __launch_bounds__(256) void gemm_k(const float* __restrict__ x,
                                              const short* __restrict__ xb16,
                                              const short* __restrict__ panels,
                                              float* __restrict__ out) {
  __shared__ short lds[2 * 128 * 64];
  short* ldsA = lds;
  short* ldsB = lds + 128 * 64;

  const int hw = blockIdx.x;
  const int q = hw & 7, j = hw >> 3;
  const int ct = j & 3;
  const int rp = ((j >> 2) << 3) | q;
  const size_t rbase = (size_t)rp * 128;

  const int tid = threadIdx.x;
  const int lane = tid & 63, wave = tid >> 6;
  const int wr = wave >> 1, wc = wave & 1;
  const int l15 = lane & 15, g = lane >> 4;

  // USEBF=0 staging indices
  const int mb8 = tid >> 4;         // 0..15
  const int koff = (tid & 15) * 4;  // 0..60
  const int chA = koff >> 3, subA = koff & 7;
  // USEBF=1 staging indices
  const int mrow = tid >> 3;  // 0..31
  const int kc8 = tid & 7;    // 0..7

  f32x4 acc[4][4];
#pragma unroll
  for (int i = 0; i < 4; ++i)
#pragma unroll
    for (int j2 = 0; j2 < 4; ++j2) acc[i][j2] = f32x4{0.f, 0.f, 0.f, 0.f};

  for (int ks = 0; ks < 8; ++ks) {
    __syncthreads();
    if (USEBF) {
      // stage A from bf16: pure copy, 16B/lane
#pragma unroll
      for (int i = 0; i < 4; ++i) {
        const int m = mrow + (i << 5);
        const s16x8 v =
            *(const s16x8*)(xb16 + (rbase + m) * D + ks * 64 + kc8 * 8);
        *(s16x8*)(ldsA + m * 64 + ((kc8 ^ SWZ8(m)) << 3)) = v;
      }
    } else {
      // stage A from fp32 with inline f2bf
#pragma unroll
      for (int i = 0; i < 8; ++i) {
        const int m = mb8 + (i << 4);
        const float4 v = *(const float4*)(x + (rbase + m) * D + ks * 64 + koff);
        s16x4 p;
        p[0] = (short)f2bf(v.x);
        p[1] = (short)f2bf(v.y);
        p[2] = (short)f2bf(v.z);
        p[3] = (short)f2bf(v.w);
        *(s16x4*)(ldsA + m * 64 + ((chA ^ SWZ8(m)) << 3) + subA) = p;
      }
    }
    // stage B: linear copy of pre-swizzled panel slice (16 KB)
    {
      const short* src = panels + ((size_t)(ct * 8 + ks) << 13) + tid * 8;
#pragma unroll
      for (int i = 0; i < 4; ++i)
        *(uint4*)(ldsB + i * 2048 + tid * 8) = *(const uint4*)(src + i * 2048);
    }
    __syncthreads();

#pragma unroll
    for (int kk = 0; kk < 2; ++kk) {
      s16x8 af[4], bfv[4];
#pragma unroll
      for (int mi = 0; mi < 4; ++mi) {
        const int m = 64 * wr + 16 * mi + l15;
        af[mi] = *(const s16x8*)(ldsA + m * 64 + ((((kk << 2) | g) ^ SWZ8(m)) << 3));
      }
#pragma unroll
      for (int nj = 0; nj < 4; ++nj) {
        const int n = 64 * wc + 16 * nj + l15;
        bfv[nj] = *(const s16x8*)(ldsB + n * 64 + ((((kk << 2) | g) ^ SWZ8(n)) << 3));
      }
#pragma unroll
      for (int mi = 0; mi < 4; ++mi)
#pragma unroll
        for (int nj = 0; nj < 4; ++nj)
          acc[mi][nj] = mfma16(af[mi], bfv[nj], acc[mi][nj]);
    }
  }

  __syncthreads();  // protect LDS before epilogue reuse

  // epilogue: per-wave transpose through LDS, then contiguous float4 NT stores
  float* scratch = (float*)lds;
  const int wbase = wave * 1088;  // 16 rows x 68 floats per wave
#pragma unroll
  for (int mi = 0; mi < 4; ++mi) {
#pragma unroll
    for (int nj = 0; nj < 4; ++nj)
#pragma unroll
      for (int r = 0; r < 4; ++r)
        scratch[wbase + (4 * g + r) * 68 + 16 * nj + l15] = acc[mi][nj][r];
    __syncthreads();
#pragma unroll
    for (int i = 0; i < 4; ++i) {
      const int rl = g + 4 * i;  // 0..15
      const f32x4 v = *(const f32x4*)&scratch[wbase + rl * 68 + l15 * 4];
      const size_t row_g = rbase + 64 * wr + 16 * mi + rl;
      const int col_g = ct * 128 + 64 * wc + l15 * 4;
      __builtin_nontemporal_store(v, (f32x4*)(out + row_g * D + col_g));
    }
    __syncthreads();
  }
}

// ---------------------------------------------------------------------------
extern "C" void kernel_launch(void* const* d_in, const int* in_sizes, int n_in,
                              void* d_out, int out_size, void* d_ws,
                              size_t ws_size, hipStream_t stream) {
  (void)in_sizes; (void)n_in; (void)out_size;
  const float* x = (const float*)d_in[0];
  const float* run = (const float*)d_in[1];
  float* out = (float*)d_out;
  uint8_t* ws = (uint8_t*)d_ws;

  float* C = (float*)ws;                           // 1 MB
  unsigned* sMax = (unsigned*)(ws + (1u << 20));   // 256 B slot
  float* M = (float*)(ws + (1u << 20) + 256);      // 1 MB
  float* Ya = M + 262144;
  float* Yb = Ya + 262144;
  float* Za = Yb + 262144;
  float* Zb = Za + 262144;
  float* T = Zb + 262144;
  short* panels = (short*)(T + 262144);            // 512 KB
  short* xb16 = panels + 262144;                   // 256 MB (optional)

  const size_t need =
      (size_t)((uint8_t*)xb16 - ws) + (size_t)N_ROWS * D * sizeof(short);
  const bool big = ws_size >= need;

  (void)hipMemsetAsync(C, 0, (1u << 20) + 256, stream);  // zero C and sMax

  covar_k<<<640, 256, 0, stream>>>(x, C, big ? xb16 : nullptr);

  {
    void* params[] = {&C, &run, &M, &sMax, &Ya, &Yb, &Za, &Zb, &T, &panels};
    (void)hipLaunchCooperativeKernel((void*)fused_mat_k, dim3(256), dim3(256),
                                     params, 0, stream);
  }

  if (big)
    gemm_k<1><<<8192, 256, 0, stream>>>(x, xb16, panels, out);
  else
    gemm_k<0><<<8192, 256, 0, stream>>>(x, xb16, panels, out);
}

// Round 5
// 779.585 us; speedup vs baseline: 1.5829x; 1.5829x over previous
//
#include <hip/hip_runtime.h>
#include <stdint.h>

// ---------------------------------------------------------------------------
// BatchWhiten: out = x @ inv_sqrtm(max(0.1*running + 0.9*(x^T x)/N, 1e-5))
// x: [262144, 512] fp32, running: [512,512] fp32, out: [262144,512] fp32
// ---------------------------------------------------------------------------

#define N_ROWS 262144
#define D 512
#define NS_ITERS 5  // 1 simplified (Z0=I) + 4 full coupled Newton-Schulz
#define CK_CHUNKS 64
#define CK_ROWS (N_ROWS / CK_CHUNKS)  // 4096
#define CK_STEPS (CK_ROWS / 32)       // 128

typedef float f32x4 __attribute__((ext_vector_type(4)));
typedef short s16x8 __attribute__((ext_vector_type(8)));
typedef short s16x4 __attribute__((ext_vector_type(4)));
typedef __bf16 bf16x8 __attribute__((ext_vector_type(8)));

static __device__ __forceinline__ unsigned short f2bf(float f) {
  unsigned u = __float_as_uint(f);
  u += 0x7FFFu + ((u >> 16) & 1u);  // RNE
  return (unsigned short)(u >> 16);
}

static __device__ __forceinline__ f32x4 mfma16(s16x8 a, s16x8 b, f32x4 c) {
  return __builtin_amdgcn_mfma_f32_16x16x32_bf16(
      __builtin_bit_cast(bf16x8, a), __builtin_bit_cast(bf16x8, b), c, 0, 0, 0);
}

// async global->LDS, 16B per lane; LDS dest = wave-uniform base + lane*16
static __device__ __forceinline__ void gld_lds16(const void* g, void* l) {
  __builtin_amdgcn_global_load_lds(
      (const __attribute__((address_space(1))) void*)g,
      (__attribute__((address_space(3))) void*)l, 16, 0, 0);
}

#define SWZ4(c) (((c) ^ ((c) >> 2)) & 3)
#define SWZ8(c) (((c) ^ ((c) >> 3)) & 7)

// ---------------------------------------------------------------------------
// Kernel 1: Cpart[xcd] += x^T x (split-K, bf16 MFMA, upper tiles mb<=nb).
// grid 640, XCD-swizzled (chunk's 10 works co-dispatched on one XCD).
// Diagonal works dump their staged bf16 tiles to xb16 (full coverage, once).
// Per-XCD partial C buffers keep the split-K atomics XCD-local.
// ---------------------------------------------------------------------------
__global__ __launch_bounds__(256) void covar_k(const float* __restrict__ x,
                                               float* __restrict__ Cpart,
                                               short* __restrict__ xb16) {
  __shared__ short ldsA[128 * 32];
  __shared__ short ldsB[128 * 32];

  const int hw = blockIdx.x;
  const int work = (hw & 7) * 80 + (hw >> 3);
  int t = work % 10, mb = 0, rl = 4;
  while (t >= rl) { t -= rl; ++mb; --rl; }
  const int nb = mb + t;
  const int chunk = work / 10;
  float* C = Cpart + (size_t)(hw & 7) * (D * D);

  const int tid = threadIdx.x;
  const int c2 = (tid & 63) * 2;  // 0,2,..,126
  const int kh = tid >> 6;        // 0..3 (k-chunk of 8)

  const int lane = tid & 63;
  const int wave = tid >> 6;
  const int wr = wave >> 1, wc = wave & 1;
  const int l15 = lane & 15, g = lane >> 4;

  const bool dump = (xb16 != nullptr) && (nb == mb);

  f32x4 acc[4][4];
#pragma unroll
  for (int i = 0; i < 4; ++i)
#pragma unroll
    for (int j = 0; j < 4; ++j) acc[i][j] = f32x4{0.f, 0.f, 0.f, 0.f};

  const size_t kbase0 = (size_t)chunk * CK_ROWS;

  for (int st = 0; st < CK_STEPS; ++st) {
    const size_t k0 = kbase0 + (size_t)st * 32;
    __syncthreads();
    {  // stage M-block
      const float* src = x + (k0 + kh * 8) * D + mb * 128 + c2;
      s16x8 p0, p1;
#pragma unroll
      for (int q = 0; q < 8; ++q) {
        float2 v = *(const float2*)(src + (size_t)q * D);
        p0[q] = (short)f2bf(v.x);
        p1[q] = (short)f2bf(v.y);
      }
      *(s16x8*)(ldsA + c2 * 32 + ((kh ^ SWZ4(c2)) << 3)) = p0;
      *(s16x8*)(ldsA + (c2 + 1) * 32 + ((kh ^ SWZ4(c2 + 1)) << 3)) = p1;
      if (dump) {
        uint32_t* xw = (uint32_t*)xb16;
        const size_t base = (k0 + kh * 8) * 256 + mb * 64 + (c2 >> 1);
#pragma unroll
        for (int q = 0; q < 8; ++q) {
          const uint32_t u =
              (uint32_t)(uint16_t)p0[q] | ((uint32_t)(uint16_t)p1[q] << 16);
          xw[base + (size_t)q * 256] = u;
        }
      }
    }
    if (nb != mb) {  // stage N-block
      const float* src = x + (k0 + kh * 8) * D + nb * 128 + c2;
      s16x8 p0, p1;
#pragma unroll
      for (int q = 0; q < 8; ++q) {
        float2 v = *(const float2*)(src + (size_t)q * D);
        p0[q] = (short)f2bf(v.x);
        p1[q] = (short)f2bf(v.y);
      }
      *(s16x8*)(ldsB + c2 * 32 + ((kh ^ SWZ4(c2)) << 3)) = p0;
      *(s16x8*)(ldsB + (c2 + 1) * 32 + ((kh ^ SWZ4(c2 + 1)) << 3)) = p1;
    }
    __syncthreads();

    const short* Bp = (nb != mb) ? ldsB : ldsA;
    s16x8 af[4], bfv[4];
#pragma unroll
    for (int mi = 0; mi < 4; ++mi) {
      int m = 64 * wr + 16 * mi + l15;
      af[mi] = *(const s16x8*)(ldsA + m * 32 + ((g ^ SWZ4(m)) << 3));
    }
#pragma unroll
    for (int nj = 0; nj < 4; ++nj) {
      int n = 64 * wc + 16 * nj + l15;
      bfv[nj] = *(const s16x8*)(Bp + n * 32 + ((g ^ SWZ4(n)) << 3));
    }
#pragma unroll
    for (int mi = 0; mi < 4; ++mi)
#pragma unroll
      for (int nj = 0; nj < 4; ++nj)
        acc[mi][nj] = mfma16(af[mi], bfv[nj], acc[mi][nj]);
  }

  // epilogue: atomic accumulate into this XCD's partial buffer
#pragma unroll
  for (int mi = 0; mi < 4; ++mi)
#pragma unroll
    for (int nj = 0; nj < 4; ++nj) {
      const int n = nb * 128 + 64 * wc + 16 * nj + l15;
#pragma unroll
      for (int r = 0; r < 4; ++r) {
        const int m = mb * 128 + 64 * wr + 16 * mi + 4 * g + r;
        atomicAdd(&C[(size_t)m * D + n], acc[mi][nj][r]);
      }
    }
}

// ---------------------------------------------------------------------------
// Kernel 2: M = max(0.1*run + (0.9/N)*sum_p Cpart[p], 1e-5); sMax = max rowsum
// ---------------------------------------------------------------------------
__global__ __launch_bounds__(256) void prep_k(const float* __restrict__ Cpart,
                                              const float* __restrict__ run,
                                              float* __restrict__ M,
                                              unsigned* __restrict__ sMax) {
  const int r = blockIdx.x;
  const int t = threadIdx.x;
  const float cs = 0.9f / (float)N_ROWS;
  float sum = 0.f;
  for (int c = t; c < D; c += 256) {
    const int rr = r < c ? r : c;
    const int cc = r < c ? c : r;
    float cv = 0.f;
#pragma unroll
    for (int p = 0; p < 8; ++p)
      cv += Cpart[(size_t)p * D * D + (size_t)rr * D + cc];
    float v = 0.1f * run[(size_t)r * D + c] + cs * cv;
    v = fmaxf(v, 1e-5f);
    M[(size_t)r * D + c] = v;
    sum += v;  // all entries positive after clamp
  }
  __shared__ float red[256];
  red[t] = sum;
  __syncthreads();
  for (int off = 128; off > 0; off >>= 1) {
    if (t < off) red[t] += red[t + off];
    __syncthreads();
  }
  if (t == 0) atomicMax(sMax, __float_as_uint(red[0]));
}

// ---------------------------------------------------------------------------
// Kernel 3: iter-1 shortcut. Y0 = M/s; T1 = 1.5I - 0.5*Y0; Z1 = T1.
// ---------------------------------------------------------------------------
__global__ __launch_bounds__(256) void init2_k(const float* __restrict__ M,
                                               const unsigned* __restrict__ sMax,
                                               float* __restrict__ Y0,
                                               float* __restrict__ T,
                                               float* __restrict__ Z1) {
  const float inv = 1.0f / __uint_as_float(*sMax);
  const int i0 = (blockIdx.x * 256 + threadIdx.x) * 4;
  const float4 m4 = *(const float4*)&M[i0];
  const int row = i0 >> 9, col0 = i0 & 511;
  float y[4], tv[4];
#pragma unroll
  for (int e = 0; e < 4; ++e) {
    y[e] = (&m4.x)[e] * inv;
    tv[e] = (row == col0 + e ? 1.5f : 0.f) - 0.5f * y[e];
  }
  *(float4*)&Y0[i0] = make_float4(y[0], y[1], y[2], y[3]);
  const float4 t4 = make_float4(tv[0], tv[1], tv[2], tv[3]);
  *(float4*)&T[i0] = t4;
  *(float4*)&Z1[i0] = t4;
}

// ---------------------------------------------------------------------------
// 512x512x512 fp32 matmul body (32x32 tile / block, 2x2 per thread)
// ---------------------------------------------------------------------------
__device__ __forceinline__ void mm512_body(const float* __restrict__ A,
                                           const float* __restrict__ B,
                                           float* a00, float* a01, float* a10,
                                           float* a11, int rbase, int cbase) {
  __shared__ float As[32][36];
  __shared__ float Bs[32][36];
  const int t = threadIdx.x;
  const int tx = t & 15, ty = t >> 4;
  const int sr = t >> 3, sc = (t & 7) * 4;
  float c00 = 0.f, c01 = 0.f, c10 = 0.f, c11 = 0.f;
  for (int k0 = 0; k0 < D; k0 += 32) {
    __syncthreads();
    *(float4*)&As[sr][sc] = *(const float4*)(A + (size_t)(rbase + sr) * D + k0 + sc);
    *(float4*)&Bs[sr][sc] = *(const float4*)(B + (size_t)(k0 + sr) * D + cbase + sc);
    __syncthreads();
#pragma unroll
    for (int kk = 0; kk < 32; ++kk) {
      const float av0 = As[2 * ty][kk], av1 = As[2 * ty + 1][kk];
      const float2 bv = *(const float2*)&Bs[kk][2 * tx];
      c00 = fmaf(av0, bv.x, c00);
      c01 = fmaf(av0, bv.y, c01);
      c10 = fmaf(av1, bv.x, c10);
      c11 = fmaf(av1, bv.y, c11);
    }
  }
  *a00 = c00; *a01 = c01; *a10 = c10; *a11 = c11;
}

// O = A @ B (plain store)
__global__ __launch_bounds__(256) void mmY_k(const float* __restrict__ A,
                                             const float* __restrict__ B,
                                             float* __restrict__ O) {
  const int rbase = blockIdx.y * 32, cbase = blockIdx.x * 32;
  float a00, a01, a10, a11;
  mm512_body(A, B, &a00, &a01, &a10, &a11, rbase, cbase);
  const int tx = threadIdx.x & 15, ty = threadIdx.x >> 4;
  const int r0 = rbase + 2 * ty, c0 = cbase + 2 * tx;
  O[(size_t)r0 * D + c0] = a00;
  O[(size_t)r0 * D + c0 + 1] = a01;
  O[(size_t)(r0 + 1) * D + c0] = a10;
  O[(size_t)(r0 + 1) * D + c0 + 1] = a11;
}

// T = 1.5 I - 0.5 * (Z @ Y)
__global__ __launch_bounds__(256) void mmT_k(const float* __restrict__ Zm,
                                             const float* __restrict__ Ym,
                                             float* __restrict__ T) {
  const int rbase = blockIdx.y * 32, cbase = blockIdx.x * 32;
  float a00, a01, a10, a11;
  mm512_body(Zm, Ym, &a00, &a01, &a10, &a11, rbase, cbase);
  const int tx = threadIdx.x & 15, ty = threadIdx.x >> 4;
  const int r0 = rbase + 2 * ty, c0 = cbase + 2 * tx;
  T[(size_t)r0 * D + c0] = (r0 == c0 ? 1.5f : 0.f) - 0.5f * a00;
  T[(size_t)r0 * D + c0 + 1] = (r0 == c0 + 1 ? 1.5f : 0.f) - 0.5f * a01;
  T[(size_t)(r0 + 1) * D + c0] = (r0 + 1 == c0 ? 1.5f : 0.f) - 0.5f * a10;
  T[(size_t)(r0 + 1) * D + c0 + 1] = (r0 + 1 == c0 + 1 ? 1.5f : 0.f) - 0.5f * a11;
}

// z=0: Ynew = Y @ T ; z=1: Znew = T @ Z
__global__ __launch_bounds__(256) void mmpair_k(const float* __restrict__ Y,
                                                const float* __restrict__ Z,
                                                const float* __restrict__ T,
                                                float* __restrict__ Yn,
                                                float* __restrict__ Zn) {
  const float* A = blockIdx.z ? T : Y;
  const float* B = blockIdx.z ? Z : T;
  float* O = blockIdx.z ? Zn : Yn;
  const int rbase = blockIdx.y * 32, cbase = blockIdx.x * 32;
  float a00, a01, a10, a11;
  mm512_body(A, B, &a00, &a01, &a10, &a11, rbase, cbase);
  const int tx = threadIdx.x & 15, ty = threadIdx.x >> 4;
  const int r0 = rbase + 2 * ty, c0 = cbase + 2 * tx;
  O[(size_t)r0 * D + c0] = a00;
  O[(size_t)r0 * D + c0 + 1] = a01;
  O[(size_t)(r0 + 1) * D + c0] = a10;
  O[(size_t)(r0 + 1) * D + c0 + 1] = a11;
}

// ---------------------------------------------------------------------------
// Kernel 4: build pre-swizzled bf16 B-panels: B = Z / sqrt(s).
// panel layout: [nb(4)][ks(8)][nl(128)][ch'(8)][e(8)] bf16  (512 KB)
// ---------------------------------------------------------------------------
__global__ __launch_bounds__(256) void panel_k(const float* __restrict__ Z,
                                               const unsigned* __restrict__ sMax,
                                               short* __restrict__ panels) {
  const float rs = rsqrtf(__uint_as_float(*sMax));
  const int i = blockIdx.x * 256 + threadIdx.x;  // 0..262143
  const int k = i >> 9, n = i & 511;
  const float v = Z[(size_t)k * D + n] * rs;
  const int nb = n >> 7, nl = n & 127;
  const int ks = k >> 6, kl = k & 63;
  const int ch = (kl >> 3) ^ SWZ8(nl), e = kl & 7;
  const size_t pi = (size_t)(((nb * 8 + ks) * 128 + nl)) * 64 + ch * 8 + e;
  panels[pi] = (short)f2bf(v);
}

// ---------------------------------------------------------------------------
// Kernel 5: out = x @ B. grid 8192 (XCD swizzle: 4 ct-sharers of a row panel
// co-dispatched on one XCD). USEBF=1: A and B staged via global_load_lds x16
// (A source pre-swizzle-XOR'd per lane, LDS linear). Epilogue: per-wave LDS
// transpose -> lane-contiguous float4 nontemporal stores.
// ---------------------------------------------------------------------------
template <int USEBF>
__global__ __launch_bounds__(256) void gemm_k(const float* __restrict__ x,
                                              const short* __restrict__ xb16,
                                              const short* __restrict__ panels,
                                              float* __restrict__ out) {
  __shared__ short lds[2 * 128 * 64];
  short* ldsA = lds;
  short* ldsB = lds + 128 * 64;

  const int hw = blockIdx.x;
  const int q = hw & 7, j = hw >> 3;
  const int ct = j & 3;
  const int rp = ((j >> 2) << 3) | q;
  const size_t rbase = (size_t)rp * 128;

  const int tid = threadIdx.x;
  const int lane = tid & 63, wave = tid >> 6;
  const int wr = wave >> 1, wc = wave & 1;
  const int l15 = lane & 15, g = lane >> 4;

  // USEBF=0 staging indices
  const int mb8 = tid >> 4;         // 0..15
  const int koff = (tid & 15) * 4;  // 0..60
  const int chA = koff >> 3, subA = koff & 7;

  f32x4 acc[4][4];
#pragma unroll
  for (int i = 0; i < 4; ++i)
#pragma unroll
    for (int j2 = 0; j2 < 4; ++j2) acc[i][j2] = f32x4{0.f, 0.f, 0.f, 0.f};

  const int wrow0 = 32 * wave;

  for (int ks = 0; ks < 8; ++ks) {
    __syncthreads();
    if (USEBF) {
      // A: wave stages rows wrow0..wrow0+31; 4 issues x 1KB; source address
      // carries the XOR swizzle, LDS dest linear.
#pragma unroll
      for (int i = 0; i < 4; ++i) {
        const int m = wrow0 + 8 * i + (lane >> 3);
        const short* src = xb16 + (rbase + m) * D + ks * 64 +
                           (((lane & 7) ^ SWZ8(m)) << 3);
        gld_lds16(src, ldsA + (wrow0 + 8 * i) * 64);
      }
    } else {
      // A from fp32 with inline f2bf
#pragma unroll
      for (int i = 0; i < 8; ++i) {
        const int m = mb8 + (i << 4);
        const float4 v = *(const float4*)(x + (rbase + m) * D + ks * 64 + koff);
        s16x4 p;
        p[0] = (short)f2bf(v.x);
        p[1] = (short)f2bf(v.y);
        p[2] = (short)f2bf(v.z);
        p[3] = (short)f2bf(v.w);
        *(s16x4*)(ldsA + m * 64 + ((chA ^ SWZ8(m)) << 3) + subA) = p;
      }
    }
    // B: linear DMA copy of pre-swizzled panel slice (16 KB)
    {
      const short* src = panels + ((size_t)(ct * 8 + ks) << 13);
#pragma unroll
      for (int i = 0; i < 4; ++i)
        gld_lds16(src + wave * 2048 + i * 512 + lane * 8,
                  ldsB + wave * 2048 + i * 512);
    }
    __syncthreads();

#pragma unroll
    for (int kk = 0; kk < 2; ++kk) {
      s16x8 af[4], bfv[4];
#pragma unroll
      for (int mi = 0; mi < 4; ++mi) {
        const int m = 64 * wr + 16 * mi + l15;
        af[mi] = *(const s16x8*)(ldsA + m * 64 + ((((kk << 2) | g) ^ SWZ8(m)) << 3));
      }
#pragma unroll
      for (int nj = 0; nj < 4; ++nj) {
        const int n = 64 * wc + 16 * nj + l15;
        bfv[nj] = *(const s16x8*)(ldsB + n * 64 + ((((kk << 2) | g) ^ SWZ8(n)) << 3));
      }
#pragma unroll
      for (int mi = 0; mi < 4; ++mi)
#pragma unroll
        for (int nj = 0; nj < 4; ++nj)
          acc[mi][nj] = mfma16(af[mi], bfv[nj], acc[mi][nj]);
    }
  }

  __syncthreads();  // protect LDS before epilogue reuse

  // epilogue: per-wave transpose through LDS, then contiguous float4 NT stores
  float* scratch = (float*)lds;
  const int wbase = wave * 1088;  // 16 rows x 68 floats per wave
#pragma unroll
  for (int mi = 0; mi < 4; ++mi) {
#pragma unroll
    for (int nj = 0; nj < 4; ++nj)
#pragma unroll
      for (int r = 0; r < 4; ++r)
        scratch[wbase + (4 * g + r) * 68 + 16 * nj + l15] = acc[mi][nj][r];
    __syncthreads();
#pragma unroll
    for (int i = 0; i < 4; ++i) {
      const int rl = g + 4 * i;  // 0..15
      const f32x4 v = *(const f32x4*)&scratch[wbase + rl * 68 + l15 * 4];
      const size_t row_g = rbase + 64 * wr + 16 * mi + rl;
      const int col_g = ct * 128 + 64 * wc + l15 * 4;
      __builtin_nontemporal_store(v, (f32x4*)(out + row_g * D + col_g));
    }
    __syncthreads();
  }
}

// ---------------------------------------------------------------------------
extern "C" void kernel_launch(void* const* d_in, const int* in_sizes, int n_in,
                              void* d_out, int out_size, void* d_ws,
                              size_t ws_size, hipStream_t stream) {
  (void)in_sizes; (void)n_in; (void)out_size;
  const float* x = (const float*)d_in[0];
  const float* run = (const float*)d_in[1];
  float* out = (float*)d_out;
  uint8_t* ws = (uint8_t*)d_ws;

  float* Cpart = (float*)ws;                          // 8 MB (8 x 1MB)
  unsigned* sMax = (unsigned*)(ws + (8u << 20));      // 256 B slot
  float* M = (float*)(ws + (8u << 20) + 256);         // 1 MB
  float* Ya = M + 262144;
  float* Yb = Ya + 262144;
  float* Za = Yb + 262144;
  float* Zb = Za + 262144;
  float* T = Zb + 262144;
  short* panels = (short*)(T + 262144);               // 512 KB
  short* xb16 = panels + 262144;                      // 256 MB (optional)

  const size_t need =
      (size_t)((uint8_t*)xb16 - ws) + (size_t)N_ROWS * D * sizeof(short);
  const bool big = ws_size >= need;

  (void)hipMemsetAsync(Cpart, 0, (8u << 20) + 256, stream);

  covar_k<<<640, 256, 0, stream>>>(x, Cpart, big ? xb16 : nullptr);
  prep_k<<<512, 256, 0, stream>>>(Cpart, run, M, sMax);

  // NS iter 1 (Z0 = I): T1 elementwise, Z1 = T1, Y1 = Y0 @ T1
  init2_k<<<256, 256, 0, stream>>>(M, sMax, Ya, T, Za);
  mmY_k<<<dim3(16, 16), 256, 0, stream>>>(Ya, T, Yb);

  // NS iters 2..NS_ITERS
  float *Y = Yb, *Z = Za, *Yn = Ya, *Zn = Zb;
  for (int it = 1; it < NS_ITERS; ++it) {
    mmT_k<<<dim3(16, 16), 256, 0, stream>>>(Z, Y, T);
    mmpair_k<<<dim3(16, 16, 2), 256, 0, stream>>>(Y, Z, T, Yn, Zn);
    float* t1 = Y; Y = Yn; Yn = t1;
    t1 = Z; Z = Zn; Zn = t1;
  }

  panel_k<<<1024, 256, 0, stream>>>(Z, sMax, panels);

  if (big)
    gemm_k<1><<<8192, 256, 0, stream>>>(x, xb16, panels, out);
  else
    gemm_k<0><<<8192, 256, 0, stream>>>(x, xb16, panels, out);
}

// Round 6
// 728.142 us; speedup vs baseline: 1.6948x; 1.0706x over previous
//
#include <hip/hip_runtime.h>
#include <stdint.h>

// ---------------------------------------------------------------------------
// BatchWhiten: out = x @ inv_sqrtm(max(0.1*running + 0.9*(x^T x)/N, 1e-5))
// x: [262144, 512] fp32, running: [512,512] fp32, out: [262144,512] fp32
// ---------------------------------------------------------------------------

#define N_ROWS 262144
#define D 512
#define NS_ITERS 4  // 1 simplified (Z0=I) + 2 full + 1 final Z-only (fused)
#define CK_CHUNKS 128
#define CK_ROWS (N_ROWS / CK_CHUNKS)  // 2048
#define CK_STEPS (CK_ROWS / 32)       // 64

typedef float f32x4 __attribute__((ext_vector_type(4)));
typedef short s16x8 __attribute__((ext_vector_type(8)));
typedef short s16x4 __attribute__((ext_vector_type(4)));
typedef __bf16 bf16x8 __attribute__((ext_vector_type(8)));

static __device__ __forceinline__ unsigned short f2bf(float f) {
  unsigned u = __float_as_uint(f);
  u += 0x7FFFu + ((u >> 16) & 1u);  // RNE
  return (unsigned short)(u >> 16);
}

static __device__ __forceinline__ f32x4 mfma16(s16x8 a, s16x8 b, f32x4 c) {
  return __builtin_amdgcn_mfma_f32_16x16x32_bf16(
      __builtin_bit_cast(bf16x8, a), __builtin_bit_cast(bf16x8, b), c, 0, 0, 0);
}

// async global->LDS, 16B per lane; LDS dest = wave-uniform base + lane*16
static __device__ __forceinline__ void gld_lds16(const void* g, void* l) {
  __builtin_amdgcn_global_load_lds(
      (const __attribute__((address_space(1))) void*)g,
      (__attribute__((address_space(3))) void*)l, 16, 0, 0);
}

#define SWZ4(c) (((c) ^ ((c) >> 2)) & 3)
#define SWZ8(c) (((c) ^ ((c) >> 3)) & 7)

// ---------------------------------------------------------------------------
// Kernel 1: Cpart[xcd] += x^T x (split-K, bf16 MFMA, upper tiles mb<=nb).
// grid 1280 (10 tiles x 128 chunks) -> 5 blocks/CU for latency hiding.
// XCD-swizzled: a chunk's 10 works sit at hw-stride-8 (co-dispatched, same
// XCD) so the chunk's 4MB k-slab is served from that XCD's L2.
// Diagonal works dump their staged bf16 tiles to xb16 (full coverage, once).
// ---------------------------------------------------------------------------
__global__ __launch_bounds__(256) void covar_k(const float* __restrict__ x,
                                               float* __restrict__ Cpart,
                                               short* __restrict__ xb16) {
  __shared__ short ldsA[128 * 32];
  __shared__ short ldsB[128 * 32];

  // bijective XCD swizzle: 1280 works = 8 XCDs x 160
  const int hw = blockIdx.x;
  const int work = (hw & 7) * 160 + (hw >> 3);
  int t = work % 10, mb = 0, rl = 4;
  while (t >= rl) { t -= rl; ++mb; --rl; }
  const int nb = mb + t;
  const int chunk = work / 10;
  float* C = Cpart + (size_t)(hw & 7) * (D * D);

  const int tid = threadIdx.x;
  const int c2 = (tid & 63) * 2;  // 0,2,..,126
  const int kh = tid >> 6;        // 0..3 (k-chunk of 8)

  const int lane = tid & 63;
  const int wave = tid >> 6;
  const int wr = wave >> 1, wc = wave & 1;
  const int l15 = lane & 15, g = lane >> 4;

  const bool dump = (xb16 != nullptr) && (nb == mb);

  f32x4 acc[4][4];
#pragma unroll
  for (int i = 0; i < 4; ++i)
#pragma unroll
    for (int j = 0; j < 4; ++j) acc[i][j] = f32x4{0.f, 0.f, 0.f, 0.f};

  const size_t kbase0 = (size_t)chunk * CK_ROWS;

  for (int st = 0; st < CK_STEPS; ++st) {
    const size_t k0 = kbase0 + (size_t)st * 32;
    __syncthreads();
    {  // stage M-block
      const float* src = x + (k0 + kh * 8) * D + mb * 128 + c2;
      s16x8 p0, p1;
#pragma unroll
      for (int q = 0; q < 8; ++q) {
        float2 v = *(const float2*)(src + (size_t)q * D);
        p0[q] = (short)f2bf(v.x);
        p1[q] = (short)f2bf(v.y);
      }
      *(s16x8*)(ldsA + c2 * 32 + ((kh ^ SWZ4(c2)) << 3)) = p0;
      *(s16x8*)(ldsA + (c2 + 1) * 32 + ((kh ^ SWZ4(c2 + 1)) << 3)) = p1;
      if (dump) {
        uint32_t* xw = (uint32_t*)xb16;
        const size_t base = (k0 + kh * 8) * 256 + mb * 64 + (c2 >> 1);
#pragma unroll
        for (int q = 0; q < 8; ++q) {
          const uint32_t u =
              (uint32_t)(uint16_t)p0[q] | ((uint32_t)(uint16_t)p1[q] << 16);
          xw[base + (size_t)q * 256] = u;
        }
      }
    }
    if (nb != mb) {  // stage N-block
      const float* src = x + (k0 + kh * 8) * D + nb * 128 + c2;
      s16x8 p0, p1;
#pragma unroll
      for (int q = 0; q < 8; ++q) {
        float2 v = *(const float2*)(src + (size_t)q * D);
        p0[q] = (short)f2bf(v.x);
        p1[q] = (short)f2bf(v.y);
      }
      *(s16x8*)(ldsB + c2 * 32 + ((kh ^ SWZ4(c2)) << 3)) = p0;
      *(s16x8*)(ldsB + (c2 + 1) * 32 + ((kh ^ SWZ4(c2 + 1)) << 3)) = p1;
    }
    __syncthreads();

    const short* Bp = (nb != mb) ? ldsB : ldsA;
    s16x8 af[4], bfv[4];
#pragma unroll
    for (int mi = 0; mi < 4; ++mi) {
      int m = 64 * wr + 16 * mi + l15;
      af[mi] = *(const s16x8*)(ldsA + m * 32 + ((g ^ SWZ4(m)) << 3));
    }
#pragma unroll
    for (int nj = 0; nj < 4; ++nj) {
      int n = 64 * wc + 16 * nj + l15;
      bfv[nj] = *(const s16x8*)(Bp + n * 32 + ((g ^ SWZ4(n)) << 3));
    }
#pragma unroll
    for (int mi = 0; mi < 4; ++mi)
#pragma unroll
      for (int nj = 0; nj < 4; ++nj)
        acc[mi][nj] = mfma16(af[mi], bfv[nj], acc[mi][nj]);
  }

  // epilogue: atomic accumulate into this XCD's partial buffer
#pragma unroll
  for (int mi = 0; mi < 4; ++mi)
#pragma unroll
    for (int nj = 0; nj < 4; ++nj) {
      const int n = nb * 128 + 64 * wc + 16 * nj + l15;
#pragma unroll
      for (int r = 0; r < 4; ++r) {
        const int m = mb * 128 + 64 * wr + 16 * mi + 4 * g + r;
        atomicAdd(&C[(size_t)m * D + n], acc[mi][nj][r]);
      }
    }
}

// ---------------------------------------------------------------------------
// Kernel 2: M = max(0.1*run + (0.9/N)*sum_p Cpart[p], 1e-5); sMax = max rowsum
// ---------------------------------------------------------------------------
__global__ __launch_bounds__(256) void prep_k(const float* __restrict__ Cpart,
                                              const float* __restrict__ run,
                                              float* __restrict__ M,
                                              unsigned* __restrict__ sMax) {
  const int r = blockIdx.x;
  const int t = threadIdx.x;
  const float cs = 0.9f / (float)N_ROWS;
  float sum = 0.f;
  for (int c = t; c < D; c += 256) {
    const int rr = r < c ? r : c;
    const int cc = r < c ? c : r;
    float cv = 0.f;
#pragma unroll
    for (int p = 0; p < 8; ++p)
      cv += Cpart[(size_t)p * D * D + (size_t)rr * D + cc];
    float v = 0.1f * run[(size_t)r * D + c] + cs * cv;
    v = fmaxf(v, 1e-5f);
    M[(size_t)r * D + c] = v;
    sum += v;  // all entries positive after clamp
  }
  __shared__ float red[256];
  red[t] = sum;
  __syncthreads();
  for (int off = 128; off > 0; off >>= 1) {
    if (t < off) red[t] += red[t + off];
    __syncthreads();
  }
  if (t == 0) atomicMax(sMax, __float_as_uint(red[0]));
}

// ---------------------------------------------------------------------------
// Kernel 3: iter-1 shortcut. Y0 = M/s; T1 = 1.5I - 0.5*Y0; Z1 = T1.
// ---------------------------------------------------------------------------
__global__ __launch_bounds__(256) void init2_k(const float* __restrict__ M,
                                               const unsigned* __restrict__ sMax,
                                               float* __restrict__ Y0,
                                               float* __restrict__ T,
                                               float* __restrict__ Z1) {
  const float inv = 1.0f / __uint_as_float(*sMax);
  const int i0 = (blockIdx.x * 256 + threadIdx.x) * 4;
  const float4 m4 = *(const float4*)&M[i0];
  const int row = i0 >> 9, col0 = i0 & 511;
  float y[4], tv[4];
#pragma unroll
  for (int e = 0; e < 4; ++e) {
    y[e] = (&m4.x)[e] * inv;
    tv[e] = (row == col0 + e ? 1.5f : 0.f) - 0.5f * y[e];
  }
  *(float4*)&Y0[i0] = make_float4(y[0], y[1], y[2], y[3]);
  const float4 t4 = make_float4(tv[0], tv[1], tv[2], tv[3]);
  *(float4*)&T[i0] = t4;
  *(float4*)&Z1[i0] = t4;
}

// ---------------------------------------------------------------------------
// 512x512x512 fp32 matmul body (32x32 tile / block, 2x2 per thread)
// ---------------------------------------------------------------------------
__device__ __forceinline__ void mm512_body(const float* __restrict__ A,
                                           const float* __restrict__ B,
                                           float* a00, float* a01, float* a10,
                                           float* a11, int rbase, int cbase) {
  __shared__ float As[32][36];
  __shared__ float Bs[32][36];
  const int t = threadIdx.x;
  const int tx = t & 15, ty = t >> 4;
  const int sr = t >> 3, sc = (t & 7) * 4;
  float c00 = 0.f, c01 = 0.f, c10 = 0.f, c11 = 0.f;
  for (int k0 = 0; k0 < D; k0 += 32) {
    __syncthreads();
    *(float4*)&As[sr][sc] = *(const float4*)(A + (size_t)(rbase + sr) * D + k0 + sc);
    *(float4*)&Bs[sr][sc] = *(const float4*)(B + (size_t)(k0 + sr) * D + cbase + sc);
    __syncthreads();
#pragma unroll
    for (int kk = 0; kk < 32; ++kk) {
      const float av0 = As[2 * ty][kk], av1 = As[2 * ty + 1][kk];
      const float2 bv = *(const float2*)&Bs[kk][2 * tx];
      c00 = fmaf(av0, bv.x, c00);
      c01 = fmaf(av0, bv.y, c01);
      c10 = fmaf(av1, bv.x, c10);
      c11 = fmaf(av1, bv.y, c11);
    }
  }
  *a00 = c00; *a01 = c01; *a10 = c10; *a11 = c11;
}

// O = A @ B (plain store)
__global__ __launch_bounds__(256) void mmY_k(const float* __restrict__ A,
                                             const float* __restrict__ B,
                                             float* __restrict__ O) {
  const int rbase = blockIdx.y * 32, cbase = blockIdx.x * 32;
  float a00, a01, a10, a11;
  mm512_body(A, B, &a00, &a01, &a10, &a11, rbase, cbase);
  const int tx = threadIdx.x & 15, ty = threadIdx.x >> 4;
  const int r0 = rbase + 2 * ty, c0 = cbase + 2 * tx;
  O[(size_t)r0 * D + c0] = a00;
  O[(size_t)r0 * D + c0 + 1] = a01;
  O[(size_t)(r0 + 1) * D + c0] = a10;
  O[(size_t)(r0 + 1) * D + c0 + 1] = a11;
}

// T = 1.5 I - 0.5 * (Z @ Y)
__global__ __launch_bounds__(256) void mmT_k(const float* __restrict__ Zm,
                                             const float* __restrict__ Ym,
                                             float* __restrict__ T) {
  const int rbase = blockIdx.y * 32, cbase = blockIdx.x * 32;
  float a00, a01, a10, a11;
  mm512_body(Zm, Ym, &a00, &a01, &a10, &a11, rbase, cbase);
  const int tx = threadIdx.x & 15, ty = threadIdx.x >> 4;
  const int r0 = rbase + 2 * ty, c0 = cbase + 2 * tx;
  T[(size_t)r0 * D + c0] = (r0 == c0 ? 1.5f : 0.f) - 0.5f * a00;
  T[(size_t)r0 * D + c0 + 1] = (r0 == c0 + 1 ? 1.5f : 0.f) - 0.5f * a01;
  T[(size_t)(r0 + 1) * D + c0] = (r0 + 1 == c0 ? 1.5f : 0.f) - 0.5f * a10;
  T[(size_t)(r0 + 1) * D + c0 + 1] = (r0 + 1 == c0 + 1 ? 1.5f : 0.f) - 0.5f * a11;
}

// z=0: Ynew = Y @ T ; z=1: Znew = T @ Z
__global__ __launch_bounds__(256) void mmpair_k(const float* __restrict__ Y,
                                                const float* __restrict__ Z,
                                                const float* __restrict__ T,
                                                float* __restrict__ Yn,
                                                float* __restrict__ Zn) {
  const float* A = blockIdx.z ? T : Y;
  const float* B = blockIdx.z ? Z : T;
  float* O = blockIdx.z ? Zn : Yn;
  const int rbase = blockIdx.y * 32, cbase = blockIdx.x * 32;
  float a00, a01, a10, a11;
  mm512_body(A, B, &a00, &a01, &a10, &a11, rbase, cbase);
  const int tx = threadIdx.x & 15, ty = threadIdx.x >> 4;
  const int r0 = rbase + 2 * ty, c0 = cbase + 2 * tx;
  O[(size_t)r0 * D + c0] = a00;
  O[(size_t)r0 * D + c0 + 1] = a01;
  O[(size_t)(r0 + 1) * D + c0] = a10;
  O[(size_t)(r0 + 1) * D + c0 + 1] = a11;
}

// ---------------------------------------------------------------------------
// Kernel 4 (final NS iter, fused): Zfinal = T @ Z, written directly as
// pre-swizzled bf16 panels scaled by 1/sqrt(s). Y-update skipped (unneeded).
// panel layout: [nb(4)][ks(8)][nl(128)][ch'(8)][e(8)] bf16  (512 KB)
// ---------------------------------------------------------------------------
__global__ __launch_bounds__(256) void mmZp_k(const float* __restrict__ T,
                                              const float* __restrict__ Z,
                                              const unsigned* __restrict__ sMax,
                                              short* __restrict__ panels) {
  const int rbase = blockIdx.y * 32, cbase = blockIdx.x * 32;
  float a00, a01, a10, a11;
  mm512_body(T, Z, &a00, &a01, &a10, &a11, rbase, cbase);
  const float rs = rsqrtf(__uint_as_float(*sMax));
  const int tx = threadIdx.x & 15, ty = threadIdx.x >> 4;
  const int r0 = rbase + 2 * ty, c0 = cbase + 2 * tx;
  const float vv[2][2] = {{a00, a01}, {a10, a11}};
#pragma unroll
  for (int dr = 0; dr < 2; ++dr)
#pragma unroll
    for (int dc = 0; dc < 2; ++dc) {
      const int k = r0 + dr, n = c0 + dc;
      const int nb_ = n >> 7, nl = n & 127;
      const int ks = k >> 6, kl = k & 63;
      const int ch = (kl >> 3) ^ SWZ8(nl), e = kl & 7;
      const size_t pi = (size_t)((nb_ * 8 + ks) * 128 + nl) * 64 + ch * 8 + e;
      panels[pi] = (short)f2bf(vv[dr][dc] * rs);
    }
}

// ---------------------------------------------------------------------------
// Kernel 5: out = x @ B. grid 8192 (XCD swizzle: 4 ct-sharers of a row panel
// co-dispatched on one XCD). USEBF=1: A and B staged via global_load_lds x16
// (A source pre-swizzle-XOR'd per lane, LDS linear). Epilogue: per-wave LDS
// transpose -> lane-contiguous float4 nontemporal stores.
// ---------------------------------------------------------------------------
template <int USEBF>
__global__ __launch_bounds__(256) void gemm_k(const float* __restrict__ x,
                                              const short* __restrict__ xb16,
                                              const short* __restrict__ panels,
                                              float* __restrict__ out) {
  __shared__ short lds[2 * 128 * 64];
  short* ldsA = lds;
  short* ldsB = lds + 128 * 64;

  const int hw = blockIdx.x;
  const int q = hw & 7, j = hw >> 3;
  const int ct = j & 3;
  const int rp = ((j >> 2) << 3) | q;
  const size_t rbase = (size_t)rp * 128;

  const int tid = threadIdx.x;
  const int lane = tid & 63, wave = tid >> 6;
  const int wr = wave >> 1, wc = wave & 1;
  const int l15 = lane & 15, g = lane >> 4;

  // USEBF=0 staging indices
  const int mb8 = tid >> 4;         // 0..15
  const int koff = (tid & 15) * 4;  // 0..60
  const int chA = koff >> 3, subA = koff & 7;

  f32x4 acc[4][4];
#pragma unroll
  for (int i = 0; i < 4; ++i)
#pragma unroll
    for (int j2 = 0; j2 < 4; ++j2) acc[i][j2] = f32x4{0.f, 0.f, 0.f, 0.f};

  const int wrow0 = 32 * wave;

  for (int ks = 0; ks < 8; ++ks) {
    __syncthreads();
    if (USEBF) {
      // A: wave stages rows wrow0..wrow0+31; 4 issues x 1KB; source address
      // carries the XOR swizzle, LDS dest linear.
#pragma unroll
      for (int i = 0; i < 4; ++i) {
        const int m = wrow0 + 8 * i + (lane >> 3);
        const short* src = xb16 + (rbase + m) * D + ks * 64 +
                           (((lane & 7) ^ SWZ8(m)) << 3);
        gld_lds16(src, ldsA + (wrow0 + 8 * i) * 64);
      }
    } else {
      // A from fp32 with inline f2bf
#pragma unroll
      for (int i = 0; i < 8; ++i) {
        const int m = mb8 + (i << 4);
        const float4 v = *(const float4*)(x + (rbase + m) * D + ks * 64 + koff);
        s16x4 p;
        p[0] = (short)f2bf(v.x);
        p[1] = (short)f2bf(v.y);
        p[2] = (short)f2bf(v.z);
        p[3] = (short)f2bf(v.w);
        *(s16x4*)(ldsA + m * 64 + ((chA ^ SWZ8(m)) << 3) + subA) = p;
      }
    }
    // B: linear DMA copy of pre-swizzled panel slice (16 KB)
    {
      const short* src = panels + ((size_t)(ct * 8 + ks) << 13);
#pragma unroll
      for (int i = 0; i < 4; ++i)
        gld_lds16(src + wave * 2048 + i * 512 + lane * 8,
                  ldsB + wave * 2048 + i * 512);
    }
    __syncthreads();

#pragma unroll
    for (int kk = 0; kk < 2; ++kk) {
      s16x8 af[4], bfv[4];
#pragma unroll
      for (int mi = 0; mi < 4; ++mi) {
        const int m = 64 * wr + 16 * mi + l15;
        af[mi] = *(const s16x8*)(ldsA + m * 64 + ((((kk << 2) | g) ^ SWZ8(m)) << 3));
      }
#pragma unroll
      for (int nj = 0; nj < 4; ++nj) {
        const int n = 64 * wc + 16 * nj + l15;
        bfv[nj] = *(const s16x8*)(ldsB + n * 64 + ((((kk << 2) | g) ^ SWZ8(n)) << 3));
      }
#pragma unroll
      for (int mi = 0; mi < 4; ++mi)
#pragma unroll
        for (int nj = 0; nj < 4; ++nj)
          acc[mi][nj] = mfma16(af[mi], bfv[nj], acc[mi][nj]);
    }
  }

  __syncthreads();  // protect LDS before epilogue reuse

  // epilogue: per-wave transpose through LDS, then contiguous float4 NT stores
  float* scratch = (float*)lds;
  const int wbase = wave * 1088;  // 16 rows x 68 floats per wave
#pragma unroll
  for (int mi = 0; mi < 4; ++mi) {
#pragma unroll
    for (int nj = 0; nj < 4; ++nj)
#pragma unroll
      for (int r = 0; r < 4; ++r)
        scratch[wbase + (4 * g + r) * 68 + 16 * nj + l15] = acc[mi][nj][r];
    __syncthreads();
#pragma unroll
    for (int i = 0; i < 4; ++i) {
      const int rl = g + 4 * i;  // 0..15
      const f32x4 v = *(const f32x4*)&scratch[wbase + rl * 68 + l15 * 4];
      const size_t row_g = rbase + 64 * wr + 16 * mi + rl;
      const int col_g = ct * 128 + 64 * wc + l15 * 4;
      __builtin_nontemporal_store(v, (f32x4*)(out + row_g * D + col_g));
    }
    __syncthreads();
  }
}

// ---------------------------------------------------------------------------
extern "C" void kernel_launch(void* const* d_in, const int* in_sizes, int n_in,
                              void* d_out, int out_size, void* d_ws,
                              size_t ws_size, hipStream_t stream) {
  (void)in_sizes; (void)n_in; (void)out_size;
  const float* x = (const float*)d_in[0];
  const float* run = (const float*)d_in[1];
  float* out = (float*)d_out;
  uint8_t* ws = (uint8_t*)d_ws;

  float* Cpart = (float*)ws;                          // 8 MB (8 x 1MB)
  unsigned* sMax = (unsigned*)(ws + (8u << 20));      // 256 B slot
  float* M = (float*)(ws + (8u << 20) + 256);         // 1 MB
  float* Ya = M + 262144;
  float* Yb = Ya + 262144;
  float* Za = Yb + 262144;
  float* Zb = Za + 262144;
  float* T = Zb + 262144;
  short* panels = (short*)(T + 262144);               // 512 KB
  short* xb16 = panels + 262144;                      // 256 MB (optional)

  const size_t need =
      (size_t)((uint8_t*)xb16 - ws) + (size_t)N_ROWS * D * sizeof(short);
  const bool big = ws_size >= need;

  (void)hipMemsetAsync(Cpart, 0, (8u << 20) + 256, stream);

  covar_k<<<1280, 256, 0, stream>>>(x, Cpart, big ? xb16 : nullptr);
  prep_k<<<512, 256, 0, stream>>>(Cpart, run, M, sMax);

  // NS iter 1 (Z0 = I): T1 elementwise, Z1 = T1, Y1 = Y0 @ T1
  init2_k<<<256, 256, 0, stream>>>(M, sMax, Ya, T, Za);
  mmY_k<<<dim3(16, 16), 256, 0, stream>>>(Ya, T, Yb);

  // NS iters 2..NS_ITERS-1 (full coupled)
  float *Y = Yb, *Z = Za, *Yn = Ya, *Zn = Zb;
  for (int it = 1; it < NS_ITERS - 1; ++it) {
    mmT_k<<<dim3(16, 16), 256, 0, stream>>>(Z, Y, T);
    mmpair_k<<<dim3(16, 16, 2), 256, 0, stream>>>(Y, Z, T, Yn, Zn);
    float* t1 = Y; Y = Yn; Yn = t1;
    t1 = Z; Z = Zn; Zn = t1;
  }

  // final NS iter: only Z needed; fused panel build
  mmT_k<<<dim3(16, 16), 256, 0, stream>>>(Z, Y, T);
  mmZp_k<<<dim3(16, 16), 256, 0, stream>>>(T, Z, sMax, panels);

  if (big)
    gemm_k<1><<<8192, 256, 0, stream>>>(x, xb16, panels, out);
  else
    gemm_k<0><<<8192, 256, 0, stream>>>(x, xb16, panels, out);
}

// Round 7
// 678.001 us; speedup vs baseline: 1.8201x; 1.0740x over previous
//
#include <hip/hip_runtime.h>
#include <stdint.h>

// ---------------------------------------------------------------------------
// BatchWhiten: out = x @ inv_sqrtm(max(0.1*running + 0.9*(x^T x)/N, 1e-5))
// x: [262144, 512] fp32, running: [512,512] fp32, out: [262144,512] fp32
// ---------------------------------------------------------------------------

#define N_ROWS 262144
#define D 512
#define NS_ITERS 3  // 1 simplified (Z0=I) + 1 full + 1 final Z-only (fused)
#define CK_CHUNKS 128
#define CK_ROWS (N_ROWS / CK_CHUNKS)  // 2048
#define CK_STEPS (CK_ROWS / 64)       // 32 (BK=64)

typedef float f32x4 __attribute__((ext_vector_type(4)));
typedef short s16x8 __attribute__((ext_vector_type(8)));
typedef short s16x4 __attribute__((ext_vector_type(4)));
typedef __bf16 bf16x8 __attribute__((ext_vector_type(8)));

static __device__ __forceinline__ unsigned short f2bf(float f) {
  unsigned u = __float_as_uint(f);
  u += 0x7FFFu + ((u >> 16) & 1u);  // RNE
  return (unsigned short)(u >> 16);
}

static __device__ __forceinline__ f32x4 mfma16(s16x8 a, s16x8 b, f32x4 c) {
  return __builtin_amdgcn_mfma_f32_16x16x32_bf16(
      __builtin_bit_cast(bf16x8, a), __builtin_bit_cast(bf16x8, b), c, 0, 0, 0);
}

// async global->LDS, 16B per lane; LDS dest = wave-uniform base + lane*16
static __device__ __forceinline__ void gld_lds16(const void* g, void* l) {
  __builtin_amdgcn_global_load_lds(
      (const __attribute__((address_space(1))) void*)g,
      (__attribute__((address_space(3))) void*)l, 16, 0, 0);
}

#define SWZ8(c) (((c) ^ ((c) >> 3)) & 7)

// ---------------------------------------------------------------------------
// Kernel 1: Cpart[xcd] += x^T x (split-K, bf16 MFMA, upper tiles mb<=nb).
// grid 1280 (10 tiles x 128 chunks), BK=64 -> 32 barrier pairs (was 64).
// XCD-swizzled: a chunk's 10 works at hw-stride-8 share one XCD's L2.
// xb16 dump balanced: every work dumps the kh==rank quarter (16 rows/step)
// of each tile it stages (A-rank = nb-mb, B-rank = 4-(nb-mb); each tile's
// 4 stagers cover ranks 0..3 exactly once). Dump stores are nontemporal.
// ---------------------------------------------------------------------------
__global__ __launch_bounds__(256) void covar_k(const float* __restrict__ x,
                                               float* __restrict__ Cpart,
                                               short* __restrict__ xb16) {
  __shared__ short ldsA[128 * 64];
  __shared__ short ldsB[128 * 64];

  // bijective XCD swizzle: 1280 works = 8 XCDs x 160
  const int hw = blockIdx.x;
  const int work = (hw & 7) * 160 + (hw >> 3);
  int t = work % 10, mb = 0, rl = 4;
  while (t >= rl) { t -= rl; ++mb; --rl; }
  const int nb = mb + t;
  const int chunk = work / 10;
  float* C = Cpart + (size_t)(hw & 7) * (D * D);

  const int tid = threadIdx.x;
  const int c2 = (tid & 63) * 2;  // columns c2, c2+1 of the tile
  const int kh = tid >> 6;        // 0..3: rows [16kh, 16kh+16) of the step

  const int lane = tid & 63;
  const int wave = tid >> 6;
  const int wr = wave >> 1, wc = wave & 1;
  const int l15 = lane & 15, g = lane >> 4;

  const bool haveDump = (xb16 != nullptr);
  const int rankA = nb - mb;        // 0 for diagonal works
  const int rankB = 4 - (nb - mb);  // only meaningful off-diagonal
  const bool dumpA = haveDump && (kh == rankA);
  const bool dumpB = haveDump && (nb != mb) && (kh == rankB);
  uint32_t* xw = (uint32_t*)xb16;

  f32x4 acc[4][4];
#pragma unroll
  for (int i = 0; i < 4; ++i)
#pragma unroll
    for (int j = 0; j < 4; ++j) acc[i][j] = f32x4{0.f, 0.f, 0.f, 0.f};

  const size_t kbase0 = (size_t)chunk * CK_ROWS;

  for (int st = 0; st < CK_STEPS; ++st) {
    const size_t k0 = kbase0 + (size_t)st * 64;
    __syncthreads();
    {  // stage M-block (tile mb)
      const float* src = x + (k0 + kh * 16) * D + mb * 128 + c2;
#pragma unroll
      for (int h = 0; h < 2; ++h) {
        s16x8 p0, p1;
#pragma unroll
        for (int q = 0; q < 8; ++q) {
          float2 v = *(const float2*)(src + (size_t)(h * 8 + q) * D);
          p0[q] = (short)f2bf(v.x);
          p1[q] = (short)f2bf(v.y);
        }
        const int ch = 2 * kh + h;
        *(s16x8*)(ldsA + c2 * 64 + ((ch ^ SWZ8(c2)) << 3)) = p0;
        *(s16x8*)(ldsA + (c2 + 1) * 64 + ((ch ^ SWZ8(c2 + 1)) << 3)) = p1;
        if (dumpA) {
#pragma unroll
          for (int q = 0; q < 8; ++q) {
            const uint32_t u = (uint32_t)(uint16_t)p0[q] |
                               ((uint32_t)(uint16_t)p1[q] << 16);
            __builtin_nontemporal_store(
                u,
                &xw[(k0 + kh * 16 + h * 8 + q) * 256 + mb * 64 + (c2 >> 1)]);
          }
        }
      }
    }
    if (nb != mb) {  // stage N-block (tile nb)
      const float* src = x + (k0 + kh * 16) * D + nb * 128 + c2;
#pragma unroll
      for (int h = 0; h < 2; ++h) {
        s16x8 p0, p1;
#pragma unroll
        for (int q = 0; q < 8; ++q) {
          float2 v = *(const float2*)(src + (size_t)(h * 8 + q) * D);
          p0[q] = (short)f2bf(v.x);
          p1[q] = (short)f2bf(v.y);
        }
        const int ch = 2 * kh + h;
        *(s16x8*)(ldsB + c2 * 64 + ((ch ^ SWZ8(c2)) << 3)) = p0;
        *(s16x8*)(ldsB + (c2 + 1) * 64 + ((ch ^ SWZ8(c2 + 1)) << 3)) = p1;
        if (dumpB) {
#pragma unroll
          for (int q = 0; q < 8; ++q) {
            const uint32_t u = (uint32_t)(uint16_t)p0[q] |
                               ((uint32_t)(uint16_t)p1[q] << 16);
            __builtin_nontemporal_store(
                u,
                &xw[(k0 + kh * 16 + h * 8 + q) * 256 + nb * 64 + (c2 >> 1)]);
          }
        }
      }
    }
    __syncthreads();

    const short* Bp = (nb != mb) ? ldsB : ldsA;
#pragma unroll
    for (int kk = 0; kk < 2; ++kk) {
      s16x8 af[4], bfv[4];
#pragma unroll
      for (int mi = 0; mi < 4; ++mi) {
        const int m = 64 * wr + 16 * mi + l15;
        af[mi] =
            *(const s16x8*)(ldsA + m * 64 + ((((kk << 2) | g) ^ SWZ8(m)) << 3));
      }
#pragma unroll
      for (int nj = 0; nj < 4; ++nj) {
        const int n = 64 * wc + 16 * nj + l15;
        bfv[nj] =
            *(const s16x8*)(Bp + n * 64 + ((((kk << 2) | g) ^ SWZ8(n)) << 3));
      }
#pragma unroll
      for (int mi = 0; mi < 4; ++mi)
#pragma unroll
        for (int nj = 0; nj < 4; ++nj)
          acc[mi][nj] = mfma16(af[mi], bfv[nj], acc[mi][nj]);
    }
  }

  // epilogue: atomic accumulate into this XCD's partial buffer
#pragma unroll
  for (int mi = 0; mi < 4; ++mi)
#pragma unroll
    for (int nj = 0; nj < 4; ++nj) {
      const int n = nb * 128 + 64 * wc + 16 * nj + l15;
#pragma unroll
      for (int r = 0; r < 4; ++r) {
        const int m = mb * 128 + 64 * wr + 16 * mi + 4 * g + r;
        atomicAdd(&C[(size_t)m * D + n], acc[mi][nj][r]);
      }
    }
}

// ---------------------------------------------------------------------------
// Kernel 2: M = max(0.1*run + (0.9/N)*sum_p Cpart[p], 1e-5); sMax = max rowsum
// ---------------------------------------------------------------------------
__global__ __launch_bounds__(256) void prep_k(const float* __restrict__ Cpart,
                                              const float* __restrict__ run,
                                              float* __restrict__ M,
                                              unsigned* __restrict__ sMax) {
  const int r = blockIdx.x;
  const int t = threadIdx.x;
  const float cs = 0.9f / (float)N_ROWS;
  float sum = 0.f;
  for (int c = t; c < D; c += 256) {
    const int rr = r < c ? r : c;
    const int cc = r < c ? c : r;
    float cv = 0.f;
#pragma unroll
    for (int p = 0; p < 8; ++p)
      cv += Cpart[(size_t)p * D * D + (size_t)rr * D + cc];
    float v = 0.1f * run[(size_t)r * D + c] + cs * cv;
    v = fmaxf(v, 1e-5f);
    M[(size_t)r * D + c] = v;
    sum += v;  // all entries positive after clamp
  }
  __shared__ float red[256];
  red[t] = sum;
  __syncthreads();
  for (int off = 128; off > 0; off >>= 1) {
    if (t < off) red[t] += red[t + off];
    __syncthreads();
  }
  if (t == 0) atomicMax(sMax, __float_as_uint(red[0]));
}

// ---------------------------------------------------------------------------
// Kernel 3: iter-1 shortcut. Y0 = M/s; T1 = 1.5I - 0.5*Y0; Z1 = T1.
// ---------------------------------------------------------------------------
__global__ __launch_bounds__(256) void init2_k(const float* __restrict__ M,
                                               const unsigned* __restrict__ sMax,
                                               float* __restrict__ Y0,
                                               float* __restrict__ T,
                                               float* __restrict__ Z1) {
  const float inv = 1.0f / __uint_as_float(*sMax);
  const int i0 = (blockIdx.x * 256 + threadIdx.x) * 4;
  const float4 m4 = *(const float4*)&M[i0];
  const int row = i0 >> 9, col0 = i0 & 511;
  float y[4], tv[4];
#pragma unroll
  for (int e = 0; e < 4; ++e) {
    y[e] = (&m4.x)[e] * inv;
    tv[e] = (row == col0 + e ? 1.5f : 0.f) - 0.5f * y[e];
  }
  *(float4*)&Y0[i0] = make_float4(y[0], y[1], y[2], y[3]);
  const float4 t4 = make_float4(tv[0], tv[1], tv[2], tv[3]);
  *(float4*)&T[i0] = t4;
  *(float4*)&Z1[i0] = t4;
}

// ---------------------------------------------------------------------------
// 512x512x512 fp32 matmul body (32x32 tile / block, 2x2 per thread)
// ---------------------------------------------------------------------------
__device__ __forceinline__ void mm512_body(const float* __restrict__ A,
                                           const float* __restrict__ B,
                                           float* a00, float* a01, float* a10,
                                           float* a11, int rbase, int cbase) {
  __shared__ float As[32][36];
  __shared__ float Bs[32][36];
  const int t = threadIdx.x;
  const int tx = t & 15, ty = t >> 4;
  const int sr = t >> 3, sc = (t & 7) * 4;
  float c00 = 0.f, c01 = 0.f, c10 = 0.f, c11 = 0.f;
  for (int k0 = 0; k0 < D; k0 += 32) {
    __syncthreads();
    *(float4*)&As[sr][sc] = *(const float4*)(A + (size_t)(rbase + sr) * D + k0 + sc);
    *(float4*)&Bs[sr][sc] = *(const float4*)(B + (size_t)(k0 + sr) * D + cbase + sc);
    __syncthreads();
#pragma unroll
    for (int kk = 0; kk < 32; ++kk) {
      const float av0 = As[2 * ty][kk], av1 = As[2 * ty + 1][kk];
      const float2 bv = *(const float2*)&Bs[kk][2 * tx];
      c00 = fmaf(av0, bv.x, c00);
      c01 = fmaf(av0, bv.y, c01);
      c10 = fmaf(av1, bv.x, c10);
      c11 = fmaf(av1, bv.y, c11);
    }
  }
  *a00 = c00; *a01 = c01; *a10 = c10; *a11 = c11;
}

// O = A @ B (plain store)
__global__ __launch_bounds__(256) void mmY_k(const float* __restrict__ A,
                                             const float* __restrict__ B,
                                             float* __restrict__ O) {
  const int rbase = blockIdx.y * 32, cbase = blockIdx.x * 32;
  float a00, a01, a10, a11;
  mm512_body(A, B, &a00, &a01, &a10, &a11, rbase, cbase);
  const int tx = threadIdx.x & 15, ty = threadIdx.x >> 4;
  const int r0 = rbase + 2 * ty, c0 = cbase + 2 * tx;
  O[(size_t)r0 * D + c0] = a00;
  O[(size_t)r0 * D + c0 + 1] = a01;
  O[(size_t)(r0 + 1) * D + c0] = a10;
  O[(size_t)(r0 + 1) * D + c0 + 1] = a11;
}

// T = 1.5 I - 0.5 * (Z @ Y)
__global__ __launch_bounds__(256) void mmT_k(const float* __restrict__ Zm,
                                             const float* __restrict__ Ym,
                                             float* __restrict__ T) {
  const int rbase = blockIdx.y * 32, cbase = blockIdx.x * 32;
  float a00, a01, a10, a11;
  mm512_body(Zm, Ym, &a00, &a01, &a10, &a11, rbase, cbase);
  const int tx = threadIdx.x & 15, ty = threadIdx.x >> 4;
  const int r0 = rbase + 2 * ty, c0 = cbase + 2 * tx;
  T[(size_t)r0 * D + c0] = (r0 == c0 ? 1.5f : 0.f) - 0.5f * a00;
  T[(size_t)r0 * D + c0 + 1] = (r0 == c0 + 1 ? 1.5f : 0.f) - 0.5f * a01;
  T[(size_t)(r0 + 1) * D + c0] = (r0 + 1 == c0 ? 1.5f : 0.f) - 0.5f * a10;
  T[(size_t)(r0 + 1) * D + c0 + 1] = (r0 + 1 == c0 + 1 ? 1.5f : 0.f) - 0.5f * a11;
}

// z=0: Ynew = Y @ T ; z=1: Znew = T @ Z
__global__ __launch_bounds__(256) void mmpair_k(const float* __restrict__ Y,
                                                const float* __restrict__ Z,
                                                const float* __restrict__ T,
                                                float* __restrict__ Yn,
                                                float* __restrict__ Zn) {
  const float* A = blockIdx.z ? T : Y;
  const float* B = blockIdx.z ? Z : T;
  float* O = blockIdx.z ? Zn : Yn;
  const int rbase = blockIdx.y * 32, cbase = blockIdx.x * 32;
  float a00, a01, a10, a11;
  mm512_body(A, B, &a00, &a01, &a10, &a11, rbase, cbase);
  const int tx = threadIdx.x & 15, ty = threadIdx.x >> 4;
  const int r0 = rbase + 2 * ty, c0 = cbase + 2 * tx;
  O[(size_t)r0 * D + c0] = a00;
  O[(size_t)r0 * D + c0 + 1] = a01;
  O[(size_t)(r0 + 1) * D + c0] = a10;
  O[(size_t)(r0 + 1) * D + c0 + 1] = a11;
}

// ---------------------------------------------------------------------------
// Kernel 4 (final NS iter, fused): Zfinal = T @ Z, written directly as
// pre-swizzled bf16 panels scaled by 1/sqrt(s). Y-update skipped (unneeded).
// panel layout: [nb(4)][ks(8)][nl(128)][ch'(8)][e(8)] bf16  (512 KB)
// ---------------------------------------------------------------------------
__global__ __launch_bounds__(256) void mmZp_k(const float* __restrict__ T,
                                              const float* __restrict__ Z,
                                              const unsigned* __restrict__ sMax,
                                              short* __restrict__ panels) {
  const int rbase = blockIdx.y * 32, cbase = blockIdx.x * 32;
  float a00, a01, a10, a11;
  mm512_body(T, Z, &a00, &a01, &a10, &a11, rbase, cbase);
  const float rs = rsqrtf(__uint_as_float(*sMax));
  const int tx = threadIdx.x & 15, ty = threadIdx.x >> 4;
  const int r0 = rbase + 2 * ty, c0 = cbase + 2 * tx;
  const float vv[2][2] = {{a00, a01}, {a10, a11}};
#pragma unroll
  for (int dr = 0; dr < 2; ++dr)
#pragma unroll
    for (int dc = 0; dc < 2; ++dc) {
      const int k = r0 + dr, n = c0 + dc;
      const int nb_ = n >> 7, nl = n & 127;
      const int ks = k >> 6, kl = k & 63;
      const int ch = (kl >> 3) ^ SWZ8(nl), e = kl & 7;
      const size_t pi = (size_t)((nb_ * 8 + ks) * 128 + nl) * 64 + ch * 8 + e;
      panels[pi] = (short)f2bf(vv[dr][dc] * rs);
    }
}

// ---------------------------------------------------------------------------
// Kernel 5: out = x @ B. grid 8192 (XCD swizzle: 4 ct-sharers of a row panel
// co-dispatched on one XCD). USEBF=1: A and B staged via global_load_lds x16
// (A source pre-swizzle-XOR'd per lane, LDS linear). Epilogue: per-wave LDS
// transpose -> lane-contiguous float4 nontemporal stores.
// ---------------------------------------------------------------------------
template <int USEBF>
__global__ __launch_bounds__(256) void gemm_k(const float* __restrict__ x,
                                              const short* __restrict__ xb16,
                                              const short* __restrict__ panels,
                                              float* __restrict__ out) {
  __shared__ short lds[2 * 128 * 64];
  short* ldsA = lds;
  short* ldsB = lds + 128 * 64;

  const int hw = blockIdx.x;
  const int q = hw & 7, j = hw >> 3;
  const int ct = j & 3;
  const int rp = ((j >> 2) << 3) | q;
  const size_t rbase = (size_t)rp * 128;

  const int tid = threadIdx.x;
  const int lane = tid & 63, wave = tid >> 6;
  const int wr = wave >> 1, wc = wave & 1;
  const int l15 = lane & 15, g = lane >> 4;

  // USEBF=0 staging indices
  const int mb8 = tid >> 4;         // 0..15
  const int koff = (tid & 15) * 4;  // 0..60
  const int chA = koff >> 3, subA = koff & 7;

  f32x4 acc[4][4];
#pragma unroll
  for (int i = 0; i < 4; ++i)
#pragma unroll
    for (int j2 = 0; j2 < 4; ++j2) acc[i][j2] = f32x4{0.f, 0.f, 0.f, 0.f};

  const int wrow0 = 32 * wave;

  for (int ks = 0; ks < 8; ++ks) {
    __syncthreads();
    if (USEBF) {
      // A: wave stages rows wrow0..wrow0+31; 4 issues x 1KB; source address
      // carries the XOR swizzle, LDS dest linear.
#pragma unroll
      for (int i = 0; i < 4; ++i) {
        const int m = wrow0 + 8 * i + (lane >> 3);
        const short* src = xb16 + (rbase + m) * D + ks * 64 +
                           (((lane & 7) ^ SWZ8(m)) << 3);
        gld_lds16(src, ldsA + (wrow0 + 8 * i) * 64);
      }
    } else {
      // A from fp32 with inline f2bf
#pragma unroll
      for (int i = 0; i < 8; ++i) {
        const int m = mb8 + (i << 4);
        const float4 v = *(const float4*)(x + (rbase + m) * D + ks * 64 + koff);
        s16x4 p;
        p[0] = (short)f2bf(v.x);
        p[1] = (short)f2bf(v.y);
        p[2] = (short)f2bf(v.z);
        p[3] = (short)f2bf(v.w);
        *(s16x4*)(ldsA + m * 64 + ((chA ^ SWZ8(m)) << 3) + subA) = p;
      }
    }
    // B: linear DMA copy of pre-swizzled panel slice (16 KB)
    {
      const short* src = panels + ((size_t)(ct * 8 + ks) << 13);
#pragma unroll
      for (int i = 0; i < 4; ++i)
        gld_lds16(src + wave * 2048 + i * 512 + lane * 8,
                  ldsB + wave * 2048 + i * 512);
    }
    __syncthreads();

#pragma unroll
    for (int kk = 0; kk < 2; ++kk) {
      s16x8 af[4], bfv[4];
#pragma unroll
      for (int mi = 0; mi < 4; ++mi) {
        const int m = 64 * wr + 16 * mi + l15;
        af[mi] = *(const s16x8*)(ldsA + m * 64 + ((((kk << 2) | g) ^ SWZ8(m)) << 3));
      }
#pragma unroll
      for (int nj = 0; nj < 4; ++nj) {
        const int n = 64 * wc + 16 * nj + l15;
        bfv[nj] = *(const s16x8*)(ldsB + n * 64 + ((((kk << 2) | g) ^ SWZ8(n)) << 3));
      }
#pragma unroll
      for (int mi = 0; mi < 4; ++mi)
#pragma unroll
        for (int nj = 0; nj < 4; ++nj)
          acc[mi][nj] = mfma16(af[mi], bfv[nj], acc[mi][nj]);
    }
  }

  __syncthreads();  // protect LDS before epilogue reuse

  // epilogue: per-wave transpose through LDS, then contiguous float4 NT stores
  float* scratch = (float*)lds;
  const int wbase = wave * 1088;  // 16 rows x 68 floats per wave
#pragma unroll
  for (int mi = 0; mi < 4; ++mi) {
#pragma unroll
    for (int nj = 0; nj < 4; ++nj)
#pragma unroll
      for (int r = 0; r < 4; ++r)
        scratch[wbase + (4 * g + r) * 68 + 16 * nj + l15] = acc[mi][nj][r];
    __syncthreads();
#pragma unroll
    for (int i = 0; i < 4; ++i) {
      const int rl = g + 4 * i;  // 0..15
      const f32x4 v = *(const f32x4*)&scratch[wbase + rl * 68 + l15 * 4];
      const size_t row_g = rbase + 64 * wr + 16 * mi + rl;
      const int col_g = ct * 128 + 64 * wc + l15 * 4;
      __builtin_nontemporal_store(v, (f32x4*)(out + row_g * D + col_g));
    }
    __syncthreads();
  }
}

// ---------------------------------------------------------------------------
extern "C" void kernel_launch(void* const* d_in, const int* in_sizes, int n_in,
                              void* d_out, int out_size, void* d_ws,
                              size_t ws_size, hipStream_t stream) {
  (void)in_sizes; (void)n_in; (void)out_size;
  const float* x = (const float*)d_in[0];
  const float* run = (const float*)d_in[1];
  float* out = (float*)d_out;
  uint8_t* ws = (uint8_t*)d_ws;

  float* Cpart = (float*)ws;                          // 8 MB (8 x 1MB)
  unsigned* sMax = (unsigned*)(ws + (8u << 20));      // 256 B slot
  float* M = (float*)(ws + (8u << 20) + 256);         // 1 MB
  float* Ya = M + 262144;
  float* Yb = Ya + 262144;
  float* Za = Yb + 262144;
  float* Zb = Za + 262144;
  float* T = Zb + 262144;
  short* panels = (short*)(T + 262144);               // 512 KB
  short* xb16 = panels + 262144;                      // 256 MB (optional)

  const size_t need =
      (size_t)((uint8_t*)xb16 - ws) + (size_t)N_ROWS * D * sizeof(short);
  const bool big = ws_size >= need;

  (void)hipMemsetAsync(Cpart, 0, (8u << 20) + 256, stream);

  covar_k<<<1280, 256, 0, stream>>>(x, Cpart, big ? xb16 : nullptr);
  prep_k<<<512, 256, 0, stream>>>(Cpart, run, M, sMax);

  // NS iter 1 (Z0 = I): T1 elementwise, Z1 = T1, Y1 = Y0 @ T1
  init2_k<<<256, 256, 0, stream>>>(M, sMax, Ya, T, Za);
  mmY_k<<<dim3(16, 16), 256, 0, stream>>>(Ya, T, Yb);

  // NS iters 2..NS_ITERS-1 (full coupled)
  float *Y = Yb, *Z = Za, *Yn = Ya, *Zn = Zb;
  for (int it = 1; it < NS_ITERS - 1; ++it) {
    mmT_k<<<dim3(16, 16), 256, 0, stream>>>(Z, Y, T);
    mmpair_k<<<dim3(16, 16, 2), 256, 0, stream>>>(Y, Z, T, Yn, Zn);
    float* t1 = Y; Y = Yn; Yn = t1;
    t1 = Z; Z = Zn; Zn = t1;
  }

  // final NS iter: only Z needed; fused panel build
  mmT_k<<<dim3(16, 16), 256, 0, stream>>>(Z, Y, T);
  mmZp_k<<<dim3(16, 16), 256, 0, stream>>>(T, Z, sMax, panels);

  if (big)
    gemm_k<1><<<8192, 256, 0, stream>>>(x, xb16, panels, out);
  else
    gemm_k<0><<<8192, 256, 0, stream>>>(x, xb16, panels, out);
}